// Round 4
// baseline (424.109 us; speedup 1.0000x reference)
//
#include <hip/hip_runtime.h>
#include <math.h>

// ---------------------------------------------------------------------------
// Decoder step. Inputs all f32 (measured by on-device detector in R2/R4 —
// now hard-coded); outputs f32. bf16 MFMA GEMMs with f32 accumulate.
// Launch graph (7 kernels):
//   setup_k  : 2048 persistent blocks: ugh-GEMM (reg-prefetch pipelined) +
//              xemb-GEMM + grid-stride f32->bf16 conversion
//   score_8p : fused score GEMM, 256x256 tile, 8-phase/2-K-tile pipeline,
//              one-phase-ahead reads, COMPILER-scheduled lgkm (no SB0 pins),
//              counted vmcnt, raw s_barrier with empty-asm fences.
//   softmax_f: partial-sum + softmax + context (4-way ILP) + x_emb pack
//   gemm_f   : gi GEMM ; gru_f ; gemm_f fc1(tanh) ; gemm_f fc2 (f32 out)
// Outputs (concat, f32): out (256x4096) | h_new (256x1024) | attn (256x128)
// ---------------------------------------------------------------------------

#define B_   256
#define L_   128
#define V_   4096
#define ENC_ 1024
#define DEC_ 1024
#define EMB_ 512
#define MB_  1048576ull

typedef __bf16 bf16;
typedef __bf16 bf16x8 __attribute__((ext_vector_type(8)));
typedef __bf16 bf16x4 __attribute__((ext_vector_type(4)));
typedef float  f32x4  __attribute__((ext_vector_type(4)));

__device__ __forceinline__ float fast_tanh(float x) {
  float e = __builtin_amdgcn_exp2f(x * 2.88539008177792681472f);
  return 1.0f - 2.0f * __builtin_amdgcn_rcpf(e + 1.0f);
}
__device__ __forceinline__ float fast_sigmoid(float x) {
  return __builtin_amdgcn_rcpf(1.0f + __builtin_amdgcn_exp2f(-1.44269504088896f * x));
}

// async 16B global->LDS copy
__device__ __forceinline__ void cp16(const void* g, void* l) {
  __builtin_amdgcn_global_load_lds(
      (const __attribute__((address_space(1))) void*)g,
      (__attribute__((address_space(3))) void*)l,
      16, 0, 0);
}

// 8 f32 -> bf16x8
__device__ __forceinline__ bf16x8 ld8f(const float* f) {
  f32x4 a = *(const f32x4*)f;
  f32x4 b = *(const f32x4*)(f + 4);
  bf16x8 r;
  r[0] = (bf16)a[0]; r[1] = (bf16)a[1]; r[2] = (bf16)a[2]; r[3] = (bf16)a[3];
  r[4] = (bf16)b[0]; r[5] = (bf16)b[1]; r[6] = (bf16)b[2]; r[7] = (bf16)b[3];
  return r;
}

// ---------------------------------------------------------------------------
// LDS XOR swizzle (R5-verified, 0 bank conflicts):
// tile slot (r, lb) [lb = 16B block 0..7] holds global cols
// k0 + ((lb ^ (r&7))*8 .. +8). Fragment read for (row ra, k-quad kq):
// offset = ra*64 + ((kq ^ (ra&7))<<3).
// ---------------------------------------------------------------------------

// 64x64-tile GEMM inner loop, f32 inputs staged manually with swizzle.
// Register-prefetch pipelined: step k+1's global loads issue before step k's
// MFMA so HBM latency hides under the compute+LDS-read phase.
__device__ __forceinline__ void gemm64_pipe(
    const float* __restrict__ A, const float* __restrict__ Brow,
    int strideA, int strideB, int kbeg, int kend, int row0,
    bf16* As, bf16* Bs, f32x4 acc[4])
{
  const int t   = threadIdx.x;
  const int lane = t & 63, w = t >> 6, q = lane >> 4, c16 = lane & 15;
  const int sr  = t >> 3, lb = t & 7;

  bf16x8 va[2], vb[2];
#pragma unroll
  for (int ch = 0; ch < 2; ch++) {
    int r    = ch * 32 + sr;
    int gcol = kbeg + ((lb ^ (r & 7)) << 3);
    va[ch] = ld8f(A    + (size_t)(row0 + r) * strideA + gcol);
    vb[ch] = ld8f(Brow + (size_t)r * strideB + gcol);
  }

  for (int k0 = kbeg; k0 < kend; k0 += 64) {
#pragma unroll
    for (int ch = 0; ch < 2; ch++) {
      *(bf16x8*)&As[ch * 2048 + t * 8] = va[ch];
      *(bf16x8*)&Bs[ch * 2048 + t * 8] = vb[ch];
    }
    __syncthreads();
    if (k0 + 64 < kend) {
#pragma unroll
      for (int ch = 0; ch < 2; ch++) {
        int r    = ch * 32 + sr;
        int gcol = k0 + 64 + ((lb ^ (r & 7)) << 3);
        va[ch] = ld8f(A    + (size_t)(row0 + r) * strideA + gcol);
        vb[ch] = ld8f(Brow + (size_t)r * strideB + gcol);
      }
    }
#pragma unroll
    for (int kkb = 0; kkb < 8; kkb += 4) {
      int rb = w * 16 + c16;
      bf16x8 bfr = *(const bf16x8*)&Bs[rb * 64 + (((kkb + q) ^ (rb & 7)) << 3)];
#pragma unroll
      for (int i = 0; i < 4; i++) {
        int ra = i * 16 + c16;
        bf16x8 af = *(const bf16x8*)&As[ra * 64 + (((kkb + q) ^ (ra & 7)) << 3)];
        acc[i] = __builtin_amdgcn_mfma_f32_16x16x32_bf16(af, bfr, acc[i], 0, 0, 0);
      }
    }
    __syncthreads();
  }
}

// ---------------------------------------------------------------------------
// setup_k: 2048 persistent blocks (8/CU exactly).
//   blocks [0,256)      : ugh GEMM  (u | gh from h0)
//   blocks [256,384)    : xemb GEMM (split-K 4)
//   blocks [384,2048)   : grid-stride f32->bf16 conversion over 10240 chunks
// ---------------------------------------------------------------------------
__global__ __launch_bounds__(256) void setup_k(
    const float* __restrict__ hidden, const float* __restrict__ W2,
    const float* __restrict__ wh, const float* __restrict__ W1_b,
    const float* __restrict__ W2_b, const float* __restrict__ gbh,
    const float* __restrict__ x, const float* __restrict__ o2e,
    const float* __restrict__ enc, const float* __restrict__ W1,
    const float* __restrict__ wi, const float* __restrict__ fc1w,
    const float* __restrict__ fc2w,
    bf16* __restrict__ enc_bf, bf16* __restrict__ W1_bf,
    bf16* __restrict__ wi_bf, bf16* __restrict__ fc1_bf,
    bf16* __restrict__ fc2_bf,
    bf16* __restrict__ u, bf16* __restrict__ gh, float* __restrict__ xe4)
{
  __shared__ __align__(16) bf16 As[64 * 64];
  __shared__ __align__(16) bf16 Bs[64 * 64];

  const int bid = blockIdx.x;
  const int t   = threadIdx.x;

  if (bid >= 384) {
    // -------- conversion role: grid-stride over 10240 16KB chunks --------
    for (int c = bid - 384; c < 10240; c += 1664) {
      const float* src; bf16* dst; int blk;
      if      (c < 8192) { src = enc;  dst = enc_bf; blk = c; }
      else if (c < 8448) { src = W1;   dst = W1_bf;  blk = c - 8192; }
      else if (c < 9600) { src = wi;   dst = wi_bf;  blk = c - 8448; }
      else if (c < 9728) { src = fc1w; dst = fc1_bf; blk = c - 9600; }
      else               { src = fc2w; dst = fc2_bf; blk = c - 9728; }
      const size_t base = (size_t)blk * 4096 + t * 16;
      const float* s = src + base;
      bf16* d = dst + base;
      *(bf16x8*)(d)     = ld8f(s);
      *(bf16x8*)(d + 8) = ld8f(s + 8);
    }
    return;
  }

  const int lane = t & 63, w = t >> 6, q = lane >> 4, c16 = lane & 15;
  f32x4 acc[4] = {};

  if (bid < 256) {
    // -------- ugh role: cols [0,1024)->u (W2, +W1_b+W2_b); rest->gh --------
    const int row0 = (bid >> 6) * 64;
    const int col0 = (bid & 63) * 64;
    const bool isU = (col0 < 1024);
    const float* Brow = isU ? (W2 + (size_t)col0 * 1024)
                            : (wh + (size_t)(col0 - 1024) * 1024);
    gemm64_pipe(hidden, Brow, 1024, 1024, 0, 1024, row0, As, Bs, acc);

    const int gc = col0 + w * 16 + c16;
    float bias = isU ? (W1_b[gc] + W2_b[gc]) : gbh[gc - 1024];
#pragma unroll
    for (int i = 0; i < 4; i++) {
      int gr0 = row0 + i * 16 + q * 4;
#pragma unroll
      for (int r = 0; r < 4; r++) {
        float v = acc[i][r] + bias;
        if (isU) u[(size_t)(gr0 + r) * 1024 + gc] = (bf16)v;
        else     gh[(size_t)(gr0 + r) * 3072 + (gc - 1024)] = (bf16)v;
      }
    }
  } else {
    // -------- xemb role: xe4[z] = x @ o2e^T over K slab z --------
    const int i3   = bid - 256;
    const int col0 = (i3 & 7) * 64;
    const int row0 = ((i3 >> 3) & 3) * 64;
    const int z    = i3 >> 5;
    gemm64_pipe(x, o2e + (size_t)col0 * 4096, 4096, 4096,
                z * 1024, z * 1024 + 1024, row0, As, Bs, acc);

    const int gc = col0 + w * 16 + c16;
    float* out = xe4 + (size_t)z * 131072;
#pragma unroll
    for (int i = 0; i < 4; i++) {
      int gr0 = row0 + i * 16 + q * 4;
#pragma unroll
      for (int r = 0; r < 4; r++)
        out[(size_t)(gr0 + r) * 512 + gc] = acc[i][r];
    }
  }
}

// ---------------------------------------------------------------------------
// score_8p: e_part[bx][row] = sum_{d in col-group bx} tanh(enc·W1 + u)*Vw
// 256x256 tile, BK=64, 512 threads (8 waves, 2M x 4N, 128x64 per wave).
// 8-phase / 2-K-tile pipeline, reads issued ONE PHASE AHEAD of their MFMA.
// Phase p: { C++ ds_reads for M(p+1) ; stage 1 half-tile (cp16) ;
//            MFMA(p) on regs read in p-1 (compiler inserts exact lgkmcnt) ;
//            [counted vmcnt at P3/P7] ; fence ; s_barrier ; fence }.
// NO manual lgkm waits / sched_barriers (m141: pinning defeats scheduler);
// empty asm memory fences pin all LDS/global ops inside their phase, while
// MFMA + addr VALU interleave freely with the ds_reads -> true overlap.
// Buffer hazard audit (stage into X >= 1 barrier after X's last reads force
// lgkm-completion via their consuming MFMA):
//   sA1 staged P1,P2 | prev reads issued P7, consumed P8 (barrier after) OK
//   sA0 staged P5,P6 | prev reads issued P3, consumed P4 OK
//   sB0 staged P3,P4 | prev reads issued P1, consumed P2 OK
//   sB1 staged P7,P8 | prev reads issued P5, consumed P6 OK
// vmcnt(2) at P3: drains B(prev P7/P8) + A(P1/P2) -> P4/P5 reads safe.
// vmcnt(2) at P7: drains B(P3/P4) + A(P5/P6)      -> P8/P1' reads safe.
// grid = 512 linear blocks, XCD-chunked bijective remap (512 % 8 == 0).
// ---------------------------------------------------------------------------
__device__ __forceinline__ void stage_half(
    const bf16* __restrict__ src, bf16* dst, int grow0, int k0, int t)
{
  const int sr = t >> 3, lb = t & 7;
#pragma unroll
  for (int ch = 0; ch < 2; ch++) {
    int r    = ch * 64 + sr;                      // row within 128-row half
    int gcol = k0 + ((lb ^ (r & 7)) << 3);        // (tile_row&7)==(r&7)
    cp16(src + (size_t)(grow0 + r) * 1024 + gcol, dst + r * 64 + lb * 8);
  }
}

#define BAR()   __builtin_amdgcn_s_barrier()
#define FENCE() asm volatile("" ::: "memory")
#define VM2()   asm volatile("s_waitcnt vmcnt(2)" ::: "memory")
#define VM4()   asm volatile("s_waitcnt vmcnt(4)" ::: "memory")
#define PHASE_END() { FENCE(); BAR(); FENCE(); }

#define RD_A4(dst, base, ib, kq)                                            \
  _Pragma("unroll") for (int i = 0; i < 4; i++) {                           \
    const int ra = ra_base + ((ib) + i) * 16;                               \
    dst[i] = *(const bf16x8*)&(base)[ra * 64 + (((kq) ^ (ra & 7)) << 3)];   \
  }
#define RD_B4(dst, base, kq)                                                \
  _Pragma("unroll") for (int j = 0; j < 4; j++) {                           \
    const int rb = rb_base + j * 16;                                        \
    dst[j] = *(const bf16x8*)&(base)[rb * 64 + (((kq) ^ (rb & 7)) << 3)];   \
  }
#define MFMA16(ib, afv, bv)                                                 \
  __builtin_amdgcn_s_setprio(1);                                            \
  _Pragma("unroll") for (int i = 0; i < 4; i++)                             \
    _Pragma("unroll") for (int j = 0; j < 4; j++)                           \
      acc[(ib) + i][j] = __builtin_amdgcn_mfma_f32_16x16x32_bf16(           \
          afv[i], bv[j], acc[(ib) + i][j], 0, 0, 0);                        \
  __builtin_amdgcn_s_setprio(0);

__global__ __launch_bounds__(512, 2) void score_8p(
    const bf16* __restrict__ A,    // enc_bf (32768 x 1024)
    const bf16* __restrict__ Bw,   // W1_bf (1024 x 1024)
    const bf16* __restrict__ u,    // (256 x 1024) bf16
    const float* __restrict__ Vw,  // (1024) f32
    float* __restrict__ e_part)    // (4 x 32768)
{
  __shared__ __align__(16) bf16 sA0[16384];      // A even tile (256x64)
  __shared__ __align__(16) bf16 sA1[16384];      // A odd tile
  __shared__ __align__(16) bf16 sB0[16384];      // B even tile
  __shared__ __align__(16) bf16 sB1[16384];      // B odd tile
  __shared__ float s_part[4][256];               // 4 KB

  const int t = threadIdx.x;
  // XCD-chunked remap: 4 col-group blocks sharing an enc slab -> same XCD
  const int wg  = blockIdx.x;
  const int swz = (wg & 7) * 64 + (wg >> 3);
  const int bx  = swz & 3;
  const int by  = swz >> 2;
  const int row0 = by * 256;
  const int col0 = bx * 256;

  const int lane = t & 63, w = t >> 6;
  const int wm = w >> 2, wn = w & 3;          // 2M x 4N wave grid
  const int q = lane >> 4, c16 = lane & 15;
  const int rb_base = wn * 64 + c16;
  const int ra_base = wm * 128 + c16;

  bf16x8 afA[4], afB[4], b0[4], b1[4];
  f32x4 acc[8][4] = {};

  // ---- prologue: stage A0, B0, B1; read M1's fragments ----
  stage_half(A,  sA0,        row0,       0,  t);
  stage_half(A,  sA0 + 8192, row0 + 128, 0,  t);
  stage_half(Bw, sB0,        col0,       0,  t);
  stage_half(Bw, sB0 + 8192, col0 + 128, 0,  t);
  stage_half(Bw, sB1,        col0,       64, t);
  stage_half(Bw, sB1 + 8192, col0 + 128, 64, t);
  VM4();            // A0+B0 complete; B1's 4 in flight
  PHASE_END();
  RD_A4(afA, sA0, 0, q);   // A(0) i0-3 kh0
  RD_B4(b0, sB0, q);       // B(0) kh0

  for (int k = 0; k < 8; ++k) {
    const int e = 2 * k, o = 2 * k + 1;
    const bool nl = (k < 7);

    // ---- P1: reads for M2; stage A(o)h0; M1 ----
    RD_A4(afB, sA0, 0, 4 + q);        // A(e) i0-3 kh1
    RD_B4(b1, sB0, 4 + q);            // B(e) kh1
    stage_half(A, sA1, row0, o * 64, t);
    MFMA16(0, afA, b0);               // M1: (e, i0-3, kh0)
    PHASE_END();

    // ---- P2: reads for M3; stage A(o)h1; M2 ----
    RD_A4(afA, sA0, 4, q);            // A(e) i4-7 kh0
    stage_half(A, sA1 + 8192, row0 + 128, o * 64, t);
    MFMA16(0, afB, b1);               // M2: (e, i0-3, kh1)
    PHASE_END();

    // ---- P3: reads for M4; stage B(e+2)h0; M3 ----
    RD_A4(afB, sA0, 4, 4 + q);        // A(e) i4-7 kh1
    if (nl) stage_half(Bw, sB0, col0, (e + 2) * 64, t);
    MFMA16(4, afA, b0);               // M3: (e, i4-7, kh0)
    VM2();                            // A(o) P1/P2 + B(o) prologue/prev done
    PHASE_END();

    // ---- P4: reads for M5; stage B(e+2)h1; M4 ----
    RD_A4(afA, sA1, 0, q);            // A(o) i0-3 kh0
    RD_B4(b0, sB1, q);                // B(o) kh0
    if (nl) stage_half(Bw, sB0 + 8192, col0 + 128, (e + 2) * 64, t);
    MFMA16(4, afB, b1);               // M4: (e, i4-7, kh1)
    PHASE_END();

    // ---- P5: reads for M6; stage A(e+2)h0; M5 ----
    RD_A4(afB, sA1, 0, 4 + q);        // A(o) i0-3 kh1
    RD_B4(b1, sB1, 4 + q);            // B(o) kh1
    if (nl) stage_half(A, sA0, row0, (e + 2) * 64, t);
    MFMA16(0, afA, b0);               // M5: (o, i0-3, kh0)
    PHASE_END();

    // ---- P6: reads for M7; stage A(e+2)h1; M6 ----
    RD_A4(afA, sA1, 4, q);            // A(o) i4-7 kh0
    if (nl) stage_half(A, sA0 + 8192, row0 + 128, (e + 2) * 64, t);
    MFMA16(0, afB, b1);               // M6: (o, i0-3, kh1)
    PHASE_END();

    // ---- P7: reads for M8; stage B(o+2)h0; M7 ----
    RD_A4(afB, sA1, 4, 4 + q);        // A(o) i4-7 kh1
    if (nl) stage_half(Bw, sB1, col0, (o + 2) * 64, t);
    MFMA16(4, afA, b0);               // M7: (o, i4-7, kh0)
    VM2();                            // A(e+2) P5/P6 + B(e+2) P3/P4 done
    PHASE_END();

    // ---- P8: reads for next M1; stage B(o+2)h1; M8 ----
    if (nl) {
      RD_A4(afA, sA0, 0, q);          // A(e+2) i0-3 kh0
      RD_B4(b0, sB0, q);              // B(e+2) kh0
      stage_half(Bw, sB1 + 8192, col0 + 128, (o + 2) * 64, t);
    }
    MFMA16(4, afB, b1);               // M8: (o, i4-7, kh1)
    PHASE_END();
  }

  // epilogue: rowsum_j tanh(acc + u[b])*Vw, reduce 16 lanes, then 4 wn-waves
  const int b = by * 2 + wm;
  float uc[4], vw[4];
#pragma unroll
  for (int j = 0; j < 4; j++) {
    const int gc = col0 + wn * 64 + j * 16 + c16;
    uc[j] = (float)u[b * 1024 + gc];
    vw[j] = Vw[gc];
  }
  float rsum[8][4];
#pragma unroll
  for (int i = 0; i < 8; i++) {
#pragma unroll
    for (int r = 0; r < 4; r++) {
      float v = 0.0f;
#pragma unroll
      for (int j = 0; j < 4; j++)
        v += fast_tanh(acc[i][j][r] + uc[j]) * vw[j];
      v += __shfl_xor(v, 1);
      v += __shfl_xor(v, 2);
      v += __shfl_xor(v, 4);
      v += __shfl_xor(v, 8);
      rsum[i][r] = v;
    }
  }
#pragma unroll
  for (int i = 0; i < 8; i++)
#pragma unroll
    for (int r = 0; r < 4; r++)
      if (c16 == 0) s_part[wn][wm * 128 + i * 16 + q * 4 + r] = rsum[i][r];
  __syncthreads();
  if (t < 256)
    e_part[(size_t)bx * 32768 + row0 + t] =
        s_part[0][t] + s_part[1][t] + s_part[2][t] + s_part[3][t];
}

// ---------------------------------------------------------------------------
// softmax + context (4-way l-split ILP) + x_emb pack. grid 256 (one per b).
// ---------------------------------------------------------------------------
__global__ __launch_bounds__(256) void softmax_f(
    const float* __restrict__ e_part, // (4, 32768)
    const bf16* __restrict__ enc,     // enc_bf
    const float* __restrict__ xe4,    // (4,256,512)
    const float* __restrict__ o2eb,   // (512)
    float* __restrict__ attn_out,     // -> d_out section 3
    bf16* __restrict__ rnn_in)        // (256,1536)
{
  const int b = blockIdx.x;
  const int t = threadIdx.x;
  __shared__ float se[128];

  if (t < 128) {
    float s = 0.0f;
#pragma unroll
    for (int cb = 0; cb < 4; cb++) s += e_part[(size_t)cb * 32768 + b * 128 + t];
    se[t] = s;
  }
  __syncthreads();

  float m = -1e30f;
  for (int l = 0; l < 128; l++) m = fmaxf(m, se[l]);
  float sum = 0.0f;
  for (int l = 0; l < 128; l++) sum += expf(se[l] - m);
  float inv = 1.0f / sum;
  __syncthreads();
  if (t < 128) {
    float p = expf(se[t] - m) * inv;
    attn_out[b * 128 + t] = p;
    se[t] = p;
  }
  __syncthreads();

  // context: thread t handles 4 contiguous k; 4 independent l-streams (ILP)
  float a0[4] = {}, a1[4] = {}, a2[4] = {}, a3[4] = {};
  const bf16* ep = enc + (size_t)b * L_ * ENC_ + t * 4;
#pragma unroll 1
  for (int l = 0; l < 32; l++) {
#pragma unroll
    for (int s = 0; s < 4; s++) {
      float p = se[l + s * 32];
      bf16x4 v = *(const bf16x4*)(ep + (size_t)(l + s * 32) * ENC_);
      a0[s] += p * (float)v[0]; a1[s] += p * (float)v[1];
      a2[s] += p * (float)v[2]; a3[s] += p * (float)v[3];
    }
  }
  bf16x4 o;
  o[0] = (bf16)(a0[0] + a0[1] + a0[2] + a0[3]);
  o[1] = (bf16)(a1[0] + a1[1] + a1[2] + a1[3]);
  o[2] = (bf16)(a2[0] + a2[1] + a2[2] + a2[3]);
  o[3] = (bf16)(a3[0] + a3[1] + a3[2] + a3[3]);
  *(bf16x4*)(rnn_in + (size_t)b * 1536 + t * 4) = o;

  // x_emb pack: rnn_in[b][1024+j] = sum_z xe4[z][b][j] + o2e_b[j]
#pragma unroll
  for (int jj = 0; jj < 2; jj++) {
    int j = jj * 256 + t;
    float v = o2eb[j];
#pragma unroll
    for (int z = 0; z < 4; z++) v += xe4[(size_t)z * 131072 + b * 512 + j];
    rnn_in[(size_t)b * 1536 + 1024 + j] = (bf16)v;
  }
}

// ---------------------------------------------------------------------------
// Generic bf16 skinny GEMM (global_load_lds + swizzle). 64x64 tile, BK=64.
// ---------------------------------------------------------------------------
template <int ACT, int OUTF32>
__global__ __launch_bounds__(256) void gemm_f(
    const bf16* __restrict__ A, const bf16* __restrict__ Bw,
    const float* __restrict__ bias1,
    void* __restrict__ C, int K, int out_ld)
{
  __shared__ __align__(16) bf16 As[64 * 64];
  __shared__ __align__(16) bf16 Bs[64 * 64];

  const int t    = threadIdx.x;
  const int lane = t & 63;
  const int w    = t >> 6;
  const int q    = lane >> 4;
  const int c16  = lane & 15;
  const int sr   = t >> 3;
  const int lb   = t & 7;
  const int row0 = blockIdx.y * 64;
  const int col0 = blockIdx.x * 64;

  f32x4 acc[4] = {};

  for (int k0 = 0; k0 < K; k0 += 64) {
#pragma unroll
    for (int ch = 0; ch < 2; ch++) {
      int r    = ch * 32 + sr;
      int gcol = k0 + ((lb ^ (r & 7)) << 3);
      cp16(A  + (size_t)(row0 + r) * K + gcol, &As[ch * 2048 + t * 8]);
      cp16(Bw + (size_t)(col0 + r) * K + gcol, &Bs[ch * 2048 + t * 8]);
    }
    __syncthreads();
#pragma unroll
    for (int kkb = 0; kkb < 8; kkb += 4) {
      int rb = w * 16 + c16;
      bf16x8 bfr = *(const bf16x8*)&Bs[rb * 64 + (((kkb + q) ^ (rb & 7)) << 3)];
#pragma unroll
      for (int i = 0; i < 4; i++) {
        int ra = i * 16 + c16;
        bf16x8 af = *(const bf16x8*)&As[ra * 64 + (((kkb + q) ^ (ra & 7)) << 3)];
        acc[i] = __builtin_amdgcn_mfma_f32_16x16x32_bf16(af, bfr, acc[i], 0, 0, 0);
      }
    }
    __syncthreads();
  }

  const int gc = col0 + w * 16 + c16;
  float bias = bias1[gc];
#pragma unroll
  for (int i = 0; i < 4; i++) {
    int gr0 = row0 + i * 16 + q * 4;
#pragma unroll
    for (int r = 0; r < 4; r++) {
      float v = acc[i][r] + bias;
      if (ACT == 1) v = fast_tanh(v);
      size_t off = (size_t)(gr0 + r) * out_ld + gc;
      if (OUTF32) ((float*)C)[off] = v;
      else        ((bf16*)C)[off] = (bf16)v;
    }
  }
}

// ---------------------------------------------------------------------------
// GRU gates. 262144 threads. h0 f32 external.
// ---------------------------------------------------------------------------
__global__ __launch_bounds__(256) void gru_f(
    const bf16* __restrict__ gi, const bf16* __restrict__ gh,
    const float* __restrict__ h0,
    float* __restrict__ hnew_out, bf16* __restrict__ hnew_i)
{
  int idx = blockIdx.x * 256 + threadIdx.x;
  int b = idx >> 10, d = idx & 1023;
  const bf16* gib = gi + b * 3072;
  const bf16* ghb = gh + b * 3072;
  float ir = (float)gib[d], iz = (float)gib[1024 + d], in = (float)gib[2048 + d];
  float hr = (float)ghb[d], hz = (float)ghb[1024 + d], hn = (float)ghb[2048 + d];
  float r = fast_sigmoid(ir + hr);
  float z = fast_sigmoid(iz + hz);
  float n = fast_tanh(in + r * hn);
  float h = (1.0f - z) * n + z * h0[idx];
  hnew_out[idx] = h;
  hnew_i[idx]   = (bf16)h;
}

// ---------------------------------------------------------------------------
extern "C" void kernel_launch(void* const* d_in, const int* in_sizes, int n_in,
                              void* d_out, int out_size, void* d_ws, size_t ws_size,
                              hipStream_t stream) {
  const float* x      = (const float*)d_in[0];
  const float* hidden = (const float*)d_in[1];
  const float* enc    = (const float*)d_in[2];
  const float* W1_w   = (const float*)d_in[3];
  const float* W1_b   = (const float*)d_in[4];
  const float* W2_w   = (const float*)d_in[5];
  const float* W2_b   = (const float*)d_in[6];
  const float* V_w    = (const float*)d_in[7];
  // d_in[8] = V_b : softmax-invariant, unused
  const float* o2e_w  = (const float*)d_in[9];
  const float* o2e_b  = (const float*)d_in[10];
  const float* gru_wi = (const float*)d_in[11];
  const float* gru_wh = (const float*)d_in[12];
  const float* gru_bi = (const float*)d_in[13];
  const float* gru_bh = (const float*)d_in[14];
  const float* fc1_w  = (const float*)d_in[15];
  const float* fc1_b  = (const float*)d_in[16];
  const float* fc2_w  = (const float*)d_in[17];
  const float* fc2_b  = (const float*)d_in[18];

  float* out_main = (float*)d_out;                      // (256,4096)
  float* out_h    = out_main + (size_t)B_ * V_;         // (256,1024)
  float* out_attn = out_h + (size_t)B_ * DEC_;          // (256,128)

  // ws layout (bytes); NEED ~88 MB (ws_size >= ~103 MB measured in R5)
  char* ws = (char*)d_ws;
  bf16*  enc_bf  = (bf16*)(ws);                    // 64 MB
  bf16*  W1_bf   = (bf16*)(ws + 64 * MB_);         // 2 MB
  bf16*  wi_bf   = (bf16*)(ws + 66 * MB_);         // 9 MB
  bf16*  fc1_bf  = (bf16*)(ws + 75 * MB_);         // 1 MB
  bf16*  fc2_bf  = (bf16*)(ws + 76 * MB_);         // 4 MB
  bf16*  u_bf    = (bf16*)(ws + 80 * MB_);         // 512 KB
  bf16*  gh_bf   = (bf16*)(ws + 80 * MB_ + 524288);      // 1.5 MB
  float* e_part  = (float*)(ws + 82 * MB_);              // 512 KB
  bf16*  gi_bf   = (bf16*)(ws + 82 * MB_ + 524288);      // 1.5 MB
  bf16*  rnn_in  = (bf16*)(ws + 84 * MB_);               // 768 KB
  bf16*  tbuf    = (bf16*)(ws + 84 * MB_ + 786432);      // 256 KB
  bf16*  hnew_bf = (bf16*)(ws + 85 * MB_);               // 512 KB
  float* xe4     = (float*)(ws + 85 * MB_ + 524288);     // 2 MB

  // 1. setup: ugh + xemb GEMMs (blocks 0..383) + grid-stride conversions
  setup_k<<<2048, 256, 0, stream>>>(
      hidden, W2_w, gru_wh, W1_b, W2_b, gru_bh, x, o2e_w,
      enc, W1_w, gru_wi, fc1_w, fc2_w,
      enc_bf, W1_bf, wi_bf, fc1_bf, fc2_bf, u_bf, gh_bf, xe4);

  // 2. score GEMM (256x256 tile, one-phase-ahead pipeline) -> e_part
  score_8p<<<512, 512, 0, stream>>>(enc_bf, W1_bf, u_bf, V_w, e_part);

  // 3. softmax + context + x_emb pack
  softmax_f<<<B_, 256, 0, stream>>>(e_part, enc_bf, xe4, o2e_b, out_attn, rnn_in);

  // 4. gi = rnn_in @ wi^T + gru_bi (256x3072, K=1536)
  gemm_f<0, 0><<<dim3(48, 4), 256, 0, stream>>>(rnn_in, wi_bf, gru_bi, gi_bf, 1536, 3072);

  // 5. GRU gates -> h_new
  gru_f<<<(B_ * DEC_) / 256, 256, 0, stream>>>(gi_bf, gh_bf, hidden, out_h, hnew_bf);

  // 6. t = tanh(h_new @ fc1^T + fc1_b) (256x512, K=1024)
  gemm_f<1, 0><<<dim3(8, 4), 256, 0, stream>>>(hnew_bf, fc1_bf, fc1_b, tbuf, 1024, 512);

  // 7. out = t @ fc2^T + fc2_b (256x4096, K=512, f32 out)
  gemm_f<0, 1><<<dim3(64, 4), 256, 0, stream>>>(tbuf, fc2_bf, fc2_b, out_main, 512, 4096);
}

// Round 6
// 409.523 us; speedup vs baseline: 1.0356x; 1.0356x over previous
//
#include <hip/hip_runtime.h>
#include <math.h>

// ---------------------------------------------------------------------------
// Decoder step. Inputs all f32 (measured by on-device detector in R2/R4 —
// now hard-coded); outputs f32. bf16 MFMA GEMMs with f32 accumulate.
// Launch graph (7 kernels):
//   setup_k  : ugh-GEMM + xemb-GEMM + small wi/fc1/fc2 f32->bf16 conversion.
//              enc/W1 conversion ELIMINATED (fused into score_rs).
//   score_rs : fused score GEMM reading f32 enc/W1 directly; reg-staged
//              (load f32 -> cvt -> swizzled ds_write), 8-phase, T14 split.
//   softmax_f: partial-sum + softmax + context (f32 enc, 4-way ILP) + x_emb
//   gemm_f   : gi GEMM ; gru_f ; gemm_f fc1(tanh) ; gemm_f fc2 (f32 out)
// Outputs (concat, f32): out (256x4096) | h_new (256x1024) | attn (256x128)
// R5 run died to container infra (no result); resubmitted unchanged.
// ---------------------------------------------------------------------------

#define B_   256
#define L_   128
#define V_   4096
#define ENC_ 1024
#define DEC_ 1024
#define EMB_ 512
#define MB_  1048576ull

typedef __bf16 bf16;
typedef __bf16 bf16x8 __attribute__((ext_vector_type(8)));
typedef __bf16 bf16x4 __attribute__((ext_vector_type(4)));
typedef float  f32x4  __attribute__((ext_vector_type(4)));

__device__ __forceinline__ float fast_tanh(float x) {
  float e = __builtin_amdgcn_exp2f(x * 2.88539008177792681472f);
  return 1.0f - 2.0f * __builtin_amdgcn_rcpf(e + 1.0f);
}
__device__ __forceinline__ float fast_sigmoid(float x) {
  return __builtin_amdgcn_rcpf(1.0f + __builtin_amdgcn_exp2f(-1.44269504088896f * x));
}

// async 16B global->LDS copy (used by gemm_f)
__device__ __forceinline__ void cp16(const void* g, void* l) {
  __builtin_amdgcn_global_load_lds(
      (const __attribute__((address_space(1))) void*)g,
      (__attribute__((address_space(3))) void*)l,
      16, 0, 0);
}

// 8 f32 -> bf16x8
__device__ __forceinline__ bf16x8 ld8f(const float* f) {
  f32x4 a = *(const f32x4*)f;
  f32x4 b = *(const f32x4*)(f + 4);
  bf16x8 r;
  r[0] = (bf16)a[0]; r[1] = (bf16)a[1]; r[2] = (bf16)a[2]; r[3] = (bf16)a[3];
  r[4] = (bf16)b[0]; r[5] = (bf16)b[1]; r[6] = (bf16)b[2]; r[7] = (bf16)b[3];
  return r;
}

// ---------------------------------------------------------------------------
// LDS XOR swizzle (verified, 0 bank conflicts): tile slot (r, s) [s = 16B
// block 0..7] holds global cols k0 + ((s ^ (r&7))*8 .. +8). Fragment read for
// (row ra, k-quad kq): offset = ra*64 + ((kq ^ (ra&7))<<3).
// ---------------------------------------------------------------------------

// 64x64-tile GEMM inner loop, f32 inputs staged manually with swizzle,
// register-prefetch pipelined.
__device__ __forceinline__ void gemm64_pipe(
    const float* __restrict__ A, const float* __restrict__ Brow,
    int strideA, int strideB, int kbeg, int kend, int row0,
    bf16* As, bf16* Bs, f32x4 acc[4])
{
  const int t   = threadIdx.x;
  const int lane = t & 63, w = t >> 6, q = lane >> 4, c16 = lane & 15;
  const int sr  = t >> 3, lb = t & 7;

  bf16x8 va[2], vb[2];
#pragma unroll
  for (int ch = 0; ch < 2; ch++) {
    int r    = ch * 32 + sr;
    int gcol = kbeg + ((lb ^ (r & 7)) << 3);
    va[ch] = ld8f(A    + (size_t)(row0 + r) * strideA + gcol);
    vb[ch] = ld8f(Brow + (size_t)r * strideB + gcol);
  }

  for (int k0 = kbeg; k0 < kend; k0 += 64) {
#pragma unroll
    for (int ch = 0; ch < 2; ch++) {
      *(bf16x8*)&As[ch * 2048 + t * 8] = va[ch];
      *(bf16x8*)&Bs[ch * 2048 + t * 8] = vb[ch];
    }
    __syncthreads();
    if (k0 + 64 < kend) {
#pragma unroll
      for (int ch = 0; ch < 2; ch++) {
        int r    = ch * 32 + sr;
        int gcol = k0 + 64 + ((lb ^ (r & 7)) << 3);
        va[ch] = ld8f(A    + (size_t)(row0 + r) * strideA + gcol);
        vb[ch] = ld8f(Brow + (size_t)r * strideB + gcol);
      }
    }
#pragma unroll
    for (int kkb = 0; kkb < 8; kkb += 4) {
      int rb = w * 16 + c16;
      bf16x8 bfr = *(const bf16x8*)&Bs[rb * 64 + (((kkb + q) ^ (rb & 7)) << 3)];
#pragma unroll
      for (int i = 0; i < 4; i++) {
        int ra = i * 16 + c16;
        bf16x8 af = *(const bf16x8*)&As[ra * 64 + (((kkb + q) ^ (ra & 7)) << 3)];
        acc[i] = __builtin_amdgcn_mfma_f32_16x16x32_bf16(af, bfr, acc[i], 0, 0, 0);
      }
    }
    __syncthreads();
  }
}

// ---------------------------------------------------------------------------
// setup_k: blocks [0,256): ugh GEMM; [256,384): xemb GEMM; [384,2176):
// one-chunk f32->bf16 conversion of wi (1152), fc1 (128), fc2 (512).
// ---------------------------------------------------------------------------
__global__ __launch_bounds__(256) void setup_k(
    const float* __restrict__ hidden, const float* __restrict__ W2,
    const float* __restrict__ wh, const float* __restrict__ W1_b,
    const float* __restrict__ W2_b, const float* __restrict__ gbh,
    const float* __restrict__ x, const float* __restrict__ o2e,
    const float* __restrict__ wi, const float* __restrict__ fc1w,
    const float* __restrict__ fc2w,
    bf16* __restrict__ wi_bf, bf16* __restrict__ fc1_bf,
    bf16* __restrict__ fc2_bf,
    bf16* __restrict__ u, bf16* __restrict__ gh, float* __restrict__ xe4)
{
  __shared__ __align__(16) bf16 As[64 * 64];
  __shared__ __align__(16) bf16 Bs[64 * 64];

  const int bid = blockIdx.x;
  const int t   = threadIdx.x;

  if (bid >= 384) {
    // -------- conversion role (wi / fc1 / fc2 only) --------
    int i = bid - 384;
    const float* src; bf16* dst; int blk;
    if      (i < 1152) { src = wi;   dst = wi_bf;  blk = i; }
    else if (i < 1280) { src = fc1w; dst = fc1_bf; blk = i - 1152; }
    else               { src = fc2w; dst = fc2_bf; blk = i - 1280; }
    const size_t base = (size_t)blk * 4096 + t * 16;
    const float* s = src + base;
    bf16* d = dst + base;
    *(bf16x8*)(d)     = ld8f(s);
    *(bf16x8*)(d + 8) = ld8f(s + 8);
    return;
  }

  const int lane = t & 63, w = t >> 6, q = lane >> 4, c16 = lane & 15;
  f32x4 acc[4] = {};

  if (bid < 256) {
    // -------- ugh role: cols [0,1024)->u (W2, +W1_b+W2_b); rest->gh --------
    const int row0 = (bid >> 6) * 64;
    const int col0 = (bid & 63) * 64;
    const bool isU = (col0 < 1024);
    const float* Brow = isU ? (W2 + (size_t)col0 * 1024)
                            : (wh + (size_t)(col0 - 1024) * 1024);
    gemm64_pipe(hidden, Brow, 1024, 1024, 0, 1024, row0, As, Bs, acc);

    const int gc = col0 + w * 16 + c16;
    float bias = isU ? (W1_b[gc] + W2_b[gc]) : gbh[gc - 1024];
#pragma unroll
    for (int i = 0; i < 4; i++) {
      int gr0 = row0 + i * 16 + q * 4;
#pragma unroll
      for (int r = 0; r < 4; r++) {
        float v = acc[i][r] + bias;
        if (isU) u[(size_t)(gr0 + r) * 1024 + gc] = (bf16)v;
        else     gh[(size_t)(gr0 + r) * 3072 + (gc - 1024)] = (bf16)v;
      }
    }
  } else {
    // -------- xemb role: xe4[z] = x @ o2e^T over K slab z --------
    const int i3   = bid - 256;
    const int col0 = (i3 & 7) * 64;
    const int row0 = ((i3 >> 3) & 3) * 64;
    const int z    = i3 >> 5;
    gemm64_pipe(x, o2e + (size_t)col0 * 4096, 4096, 4096,
                z * 1024, z * 1024 + 1024, row0, As, Bs, acc);

    const int gc = col0 + w * 16 + c16;
    float* out = xe4 + (size_t)z * 131072;
#pragma unroll
    for (int i = 0; i < 4; i++) {
      int gr0 = row0 + i * 16 + q * 4;
#pragma unroll
      for (int r = 0; r < 4; r++)
        out[(size_t)(gr0 + r) * 512 + gc] = acc[i][r];
    }
  }
}

// ---------------------------------------------------------------------------
// score_rs: e_part[bx][row] = sum_{d in col-group bx} tanh(enc·W1 + u)*Vw
// Reads f32 enc/W1 DIRECTLY (conversion fused; no enc_bf anywhere).
// 256x256 tile, BK=64, 512 threads (8 waves, 2M x 4N, 128x64 per wave).
// 8-phase / 2-K-tile pipeline, reg-staged (T14 issue-early/write-late):
//   phase p: { issue 4 global f32x4 loads (half-tile for W at p+1) ;
//              cvt + 2 swizzled ds_write_b128 (half loaded at p-1) ; FENCE ;
//              in-phase frag ds_reads ; 16 MFMA (compiler lgkm) ; barrier }
// All waits compiler-derived (no cp16 -> no manual vmcnt). FENCE between
// W and RD fixes issue order; in-order DS retire => the MFMA's read-wait
// also retires this phase's writes before the publishing barrier.
// Write slots (buffer free exactly then — audited):
//   W-P1 A(o)h0 [old sA1.h0 last read P8-prev]   W-P2 A(o)h1 [P8-prev]
//   W-P3 B(e+2)h0 [sB0 last read P2]             W-P4 B(e+2)h1 [P2]
//   W-P5 A(e+2)h0 [sA0 last read P4]             W-P6 A(e+2)h1 [P4]
//   W-P7 B(o+2)h0 [sB1 last read P6]             W-P8 B(o+2)h1 [P6]
// Load slots: 1 phase before the matching W (rA/rB ping-pong, static names).
// grid = 512 linear blocks, XCD-chunked bijective remap (512 % 8 == 0).
// ---------------------------------------------------------------------------
__device__ __forceinline__ void load_half(
    const float* __restrict__ src, int grow0, int k0, int t, f32x4 lv[4])
{
  const int sr = t >> 3, lb = t & 7;
  const float* p0 = src + (size_t)(grow0 + sr) * 1024 + k0 + lb * 8;
  const float* p1 = src + (size_t)(grow0 + 64 + sr) * 1024 + k0 + lb * 8;
  lv[0] = *(const f32x4*)p0; lv[1] = *(const f32x4*)(p0 + 4);
  lv[2] = *(const f32x4*)p1; lv[3] = *(const f32x4*)(p1 + 4);
}

__device__ __forceinline__ void write_half(bf16* dst, int t, const f32x4 lv[4])
{
  const int sr = t >> 3, lb = t & 7;
#pragma unroll
  for (int ch = 0; ch < 2; ch++) {
    const int r = ch * 64 + sr;
    const f32x4 a = lv[ch * 2], b = lv[ch * 2 + 1];
    bf16x8 o;
    o[0] = (bf16)a[0]; o[1] = (bf16)a[1]; o[2] = (bf16)a[2]; o[3] = (bf16)a[3];
    o[4] = (bf16)b[0]; o[5] = (bf16)b[1]; o[6] = (bf16)b[2]; o[7] = (bf16)b[3];
    // swizzled LDS write: slot s = lb^(r&7) holds cols (s^(r&7))*8 == lb*8
    *(bf16x8*)&dst[r * 64 + ((lb ^ (r & 7)) << 3)] = o;
  }
}

#define BAR()   __builtin_amdgcn_s_barrier()
#define FENCE() asm volatile("" ::: "memory")
#define PHASE_END() { FENCE(); BAR(); FENCE(); }

#define RD_A4(dst, base, ib, kq)                                            \
  _Pragma("unroll") for (int i = 0; i < 4; i++) {                           \
    const int ra = ra_base + ((ib) + i) * 16;                               \
    dst[i] = *(const bf16x8*)&(base)[ra * 64 + (((kq) ^ (ra & 7)) << 3)];   \
  }
#define RD_B4(dst, base, kq)                                                \
  _Pragma("unroll") for (int j = 0; j < 4; j++) {                           \
    const int rb = rb_base + j * 16;                                        \
    dst[j] = *(const bf16x8*)&(base)[rb * 64 + (((kq) ^ (rb & 7)) << 3)];   \
  }
#define MFMA16(ib, afv, bv)                                                 \
  __builtin_amdgcn_s_setprio(1);                                            \
  _Pragma("unroll") for (int i = 0; i < 4; i++)                             \
    _Pragma("unroll") for (int j = 0; j < 4; j++)                           \
      acc[(ib) + i][j] = __builtin_amdgcn_mfma_f32_16x16x32_bf16(           \
          afv[i], bv[j], acc[(ib) + i][j], 0, 0, 0);                        \
  __builtin_amdgcn_s_setprio(0);

__global__ __launch_bounds__(512, 2) void score_rs(
    const float* __restrict__ A,   // enc f32 (32768 x 1024)
    const float* __restrict__ Bw,  // W1 f32 (1024 x 1024)
    const bf16* __restrict__ u,    // (256 x 1024) bf16
    const float* __restrict__ Vw,  // (1024) f32
    float* __restrict__ e_part)    // (4 x 32768)
{
  __shared__ __align__(16) bf16 sA0[16384];      // A even tile (256x64)
  __shared__ __align__(16) bf16 sA1[16384];      // A odd tile
  __shared__ __align__(16) bf16 sB0[16384];      // B even tile
  __shared__ __align__(16) bf16 sB1[16384];      // B odd tile
  __shared__ float s_part[4][256];

  const int t = threadIdx.x;
  const int wg  = blockIdx.x;
  const int swz = (wg & 7) * 64 + (wg >> 3);
  const int bx  = swz & 3;
  const int by  = swz >> 2;
  const int row0 = by * 256;
  const int col0 = bx * 256;

  const int lane = t & 63, w = t >> 6;
  const int wm = w >> 2, wn = w & 3;          // 2M x 4N wave grid
  const int q = lane >> 4, c16 = lane & 15;
  const int rb_base = wn * 64 + c16;
  const int ra_base = wm * 128 + c16;

  bf16x8 af[4], b0[4], b1[4];
  f32x4 rA[4], rB[4];
  f32x4 acc[8][4] = {};

  // ---- prologue: stage A0, B0, B1 (load/write interleaved); preload A(1)h0
  load_half(A,  row0,        0,  t, rA);
  load_half(A,  row0 + 128,  0,  t, rB);  write_half(sA0,        t, rA);
  load_half(Bw, col0,        0,  t, rA);  write_half(sA0 + 8192, t, rB);
  load_half(Bw, col0 + 128,  0,  t, rB);  write_half(sB0,        t, rA);
  load_half(Bw, col0,        64, t, rA);  write_half(sB0 + 8192, t, rB);
  load_half(Bw, col0 + 128,  64, t, rB);  write_half(sB1,        t, rA);
  load_half(A,  row0,        64, t, rA);  write_half(sB1 + 8192, t, rB);
  asm volatile("s_waitcnt lgkmcnt(0)" ::: "memory");  // publish prologue writes
  BAR(); FENCE();

  for (int k = 0; k < 8; ++k) {
    const int e = 2 * k, o = 2 * k + 1;
    const bool nl = (k < 7);

    // ---- P1: L A(o)h1 ; W A(o)h0 ; M1 (e, i0-3, kh0) ----
    load_half(A, row0 + 128, o * 64, t, rB);
    write_half(sA1, t, rA);
    FENCE();
    RD_A4(af, sA0, 0, q); RD_B4(b0, sB0, q);
    MFMA16(0, af, b0);
    PHASE_END();

    // ---- P2: L B(e+2)h0 ; W A(o)h1 ; M2 (e, i0-3, kh1) ----
    if (nl) load_half(Bw, col0, (e + 2) * 64, t, rA);
    write_half(sA1 + 8192, t, rB);
    FENCE();
    RD_A4(af, sA0, 0, 4 + q); RD_B4(b1, sB0, 4 + q);
    MFMA16(0, af, b1);
    PHASE_END();

    // ---- P3: L B(e+2)h1 ; W B(e+2)h0 ; M3 (e, i4-7, kh0) ----
    if (nl) {
      load_half(Bw, col0 + 128, (e + 2) * 64, t, rB);
      write_half(sB0, t, rA);
    }
    FENCE();
    RD_A4(af, sA0, 4, q);
    MFMA16(4, af, b0);
    PHASE_END();

    // ---- P4: L A(e+2)h0 ; W B(e+2)h1 ; M4 (e, i4-7, kh1) ----
    if (nl) {
      load_half(A, row0, (e + 2) * 64, t, rA);
      write_half(sB0 + 8192, t, rB);
    }
    FENCE();
    RD_A4(af, sA0, 4, 4 + q);
    MFMA16(4, af, b1);
    PHASE_END();

    // ---- P5: L A(e+2)h1 ; W A(e+2)h0 ; M5 (o, i0-3, kh0) ----
    if (nl) {
      load_half(A, row0 + 128, (e + 2) * 64, t, rB);
      write_half(sA0, t, rA);
    }
    FENCE();
    RD_A4(af, sA1, 0, q); RD_B4(b0, sB1, q);
    MFMA16(0, af, b0);
    PHASE_END();

    // ---- P6: L B(o+2)h0 ; W A(e+2)h1 ; M6 (o, i0-3, kh1) ----
    if (nl) {
      load_half(Bw, col0, (o + 2) * 64, t, rA);
      write_half(sA0 + 8192, t, rB);
    }
    FENCE();
    RD_A4(af, sA1, 0, 4 + q); RD_B4(b1, sB1, 4 + q);
    MFMA16(0, af, b1);
    PHASE_END();

    // ---- P7: L B(o+2)h1 ; W B(o+2)h0 ; M7 (o, i4-7, kh0) ----
    if (nl) {
      load_half(Bw, col0 + 128, (o + 2) * 64, t, rB);
      write_half(sB1, t, rA);
    }
    FENCE();
    RD_A4(af, sA1, 4, q);
    MFMA16(4, af, b0);
    PHASE_END();

    // ---- P8: L A(o+2)h0 ; W B(o+2)h1 ; M8 (o, i4-7, kh1) ----
    if (nl) {
      load_half(A, row0, (o + 2) * 64, t, rA);
      write_half(sB1 + 8192, t, rB);
    }
    FENCE();
    RD_A4(af, sA1, 4, 4 + q);
    MFMA16(4, af, b1);
    PHASE_END();
  }

  // epilogue: rowsum_j tanh(acc + u[b])*Vw, reduce 16 lanes, then 4 wn-waves
  const int b = by * 2 + wm;
  float uc[4], vw[4];
#pragma unroll
  for (int j = 0; j < 4; j++) {
    const int gc = col0 + wn * 64 + j * 16 + c16;
    uc[j] = (float)u[b * 1024 + gc];
    vw[j] = Vw[gc];
  }
  float rsum[8][4];
#pragma unroll
  for (int i = 0; i < 8; i++) {
#pragma unroll
    for (int r = 0; r < 4; r++) {
      float v = 0.0f;
#pragma unroll
      for (int j = 0; j < 4; j++)
        v += fast_tanh(acc[i][j][r] + uc[j]) * vw[j];
      v += __shfl_xor(v, 1);
      v += __shfl_xor(v, 2);
      v += __shfl_xor(v, 4);
      v += __shfl_xor(v, 8);
      rsum[i][r] = v;
    }
  }
#pragma unroll
  for (int i = 0; i < 8; i++)
#pragma unroll
    for (int r = 0; r < 4; r++)
      if (c16 == 0) s_part[wn][wm * 128 + i * 16 + q * 4 + r] = rsum[i][r];
  __syncthreads();
  if (t < 256)
    e_part[(size_t)bx * 32768 + row0 + t] =
        s_part[0][t] + s_part[1][t] + s_part[2][t] + s_part[3][t];
}

// ---------------------------------------------------------------------------
// softmax + context (f32 enc, 4-way l-split ILP) + x_emb pack. grid 256.
// ---------------------------------------------------------------------------
__global__ __launch_bounds__(256) void softmax_f(
    const float* __restrict__ e_part, // (4, 32768)
    const float* __restrict__ enc,    // enc f32 (L3-resident after score)
    const float* __restrict__ xe4,    // (4,256,512)
    const float* __restrict__ o2eb,   // (512)
    float* __restrict__ attn_out,     // -> d_out section 3
    bf16* __restrict__ rnn_in)        // (256,1536)
{
  const int b = blockIdx.x;
  const int t = threadIdx.x;
  __shared__ float se[128];

  if (t < 128) {
    float s = 0.0f;
#pragma unroll
    for (int cb = 0; cb < 4; cb++) s += e_part[(size_t)cb * 32768 + b * 128 + t];
    se[t] = s;
  }
  __syncthreads();

  float m = -1e30f;
  for (int l = 0; l < 128; l++) m = fmaxf(m, se[l]);
  float sum = 0.0f;
  for (int l = 0; l < 128; l++) sum += expf(se[l] - m);
  float inv = 1.0f / sum;
  __syncthreads();
  if (t < 128) {
    float p = expf(se[t] - m) * inv;
    attn_out[b * 128 + t] = p;
    se[t] = p;
  }
  __syncthreads();

  // context: thread t handles 4 contiguous k; 4 independent l-streams (ILP)
  float a0[4] = {}, a1[4] = {}, a2[4] = {}, a3[4] = {};
  const float* ep = enc + (size_t)b * L_ * ENC_ + t * 4;
#pragma unroll 1
  for (int l = 0; l < 32; l++) {
#pragma unroll
    for (int s = 0; s < 4; s++) {
      float p = se[l + s * 32];
      f32x4 v = *(const f32x4*)(ep + (size_t)(l + s * 32) * ENC_);
      a0[s] += p * (float)(bf16)v[0]; a1[s] += p * (float)(bf16)v[1];
      a2[s] += p * (float)(bf16)v[2]; a3[s] += p * (float)(bf16)v[3];
    }
  }
  bf16x4 o;
  o[0] = (bf16)(a0[0] + a0[1] + a0[2] + a0[3]);
  o[1] = (bf16)(a1[0] + a1[1] + a1[2] + a1[3]);
  o[2] = (bf16)(a2[0] + a2[1] + a2[2] + a2[3]);
  o[3] = (bf16)(a3[0] + a3[1] + a3[2] + a3[3]);
  *(bf16x4*)(rnn_in + (size_t)b * 1536 + t * 4) = o;

  // x_emb pack: rnn_in[b][1024+j] = sum_z xe4[z][b][j] + o2e_b[j]
#pragma unroll
  for (int jj = 0; jj < 2; jj++) {
    int j = jj * 256 + t;
    float v = o2eb[j];
#pragma unroll
    for (int z = 0; z < 4; z++) v += xe4[(size_t)z * 131072 + b * 512 + j];
    rnn_in[(size_t)b * 1536 + 1024 + j] = (bf16)v;
  }
}

// ---------------------------------------------------------------------------
// Generic bf16 skinny GEMM (global_load_lds + swizzle). 64x64 tile, BK=64.
// ---------------------------------------------------------------------------
template <int ACT, int OUTF32>
__global__ __launch_bounds__(256) void gemm_f(
    const bf16* __restrict__ A, const bf16* __restrict__ Bw,
    const float* __restrict__ bias1,
    void* __restrict__ C, int K, int out_ld)
{
  __shared__ __align__(16) bf16 As[64 * 64];
  __shared__ __align__(16) bf16 Bs[64 * 64];

  const int t    = threadIdx.x;
  const int lane = t & 63;
  const int w    = t >> 6;
  const int q    = lane >> 4;
  const int c16  = lane & 15;
  const int sr   = t >> 3;
  const int lb   = t & 7;
  const int row0 = blockIdx.y * 64;
  const int col0 = blockIdx.x * 64;

  f32x4 acc[4] = {};

  for (int k0 = 0; k0 < K; k0 += 64) {
#pragma unroll
    for (int ch = 0; ch < 2; ch++) {
      int r    = ch * 32 + sr;
      int gcol = k0 + ((lb ^ (r & 7)) << 3);
      cp16(A  + (size_t)(row0 + r) * K + gcol, &As[ch * 2048 + t * 8]);
      cp16(Bw + (size_t)(col0 + r) * K + gcol, &Bs[ch * 2048 + t * 8]);
    }
    __syncthreads();
#pragma unroll
    for (int kkb = 0; kkb < 8; kkb += 4) {
      int rb = w * 16 + c16;
      bf16x8 bfr = *(const bf16x8*)&Bs[rb * 64 + (((kkb + q) ^ (rb & 7)) << 3)];
#pragma unroll
      for (int i = 0; i < 4; i++) {
        int ra = i * 16 + c16;
        bf16x8 af = *(const bf16x8*)&As[ra * 64 + (((kkb + q) ^ (ra & 7)) << 3)];
        acc[i] = __builtin_amdgcn_mfma_f32_16x16x32_bf16(af, bfr, acc[i], 0, 0, 0);
      }
    }
    __syncthreads();
  }

  const int gc = col0 + w * 16 + c16;
  float bias = bias1[gc];
#pragma unroll
  for (int i = 0; i < 4; i++) {
    int gr0 = row0 + i * 16 + q * 4;
#pragma unroll
    for (int r = 0; r < 4; r++) {
      float v = acc[i][r] + bias;
      if (ACT == 1) v = fast_tanh(v);
      size_t off = (size_t)(gr0 + r) * out_ld + gc;
      if (OUTF32) ((float*)C)[off] = v;
      else        ((bf16*)C)[off] = (bf16)v;
    }
  }
}

// ---------------------------------------------------------------------------
// GRU gates. 262144 threads. h0 f32 external.
// ---------------------------------------------------------------------------
__global__ __launch_bounds__(256) void gru_f(
    const bf16* __restrict__ gi, const bf16* __restrict__ gh,
    const float* __restrict__ h0,
    float* __restrict__ hnew_out, bf16* __restrict__ hnew_i)
{
  int idx = blockIdx.x * 256 + threadIdx.x;
  int b = idx >> 10, d = idx & 1023;
  const bf16* gib = gi + b * 3072;
  const bf16* ghb = gh + b * 3072;
  float ir = (float)gib[d], iz = (float)gib[1024 + d], in = (float)gib[2048 + d];
  float hr = (float)ghb[d], hz = (float)ghb[1024 + d], hn = (float)ghb[2048 + d];
  float r = fast_sigmoid(ir + hr);
  float z = fast_sigmoid(iz + hz);
  float n = fast_tanh(in + r * hn);
  float h = (1.0f - z) * n + z * h0[idx];
  hnew_out[idx] = h;
  hnew_i[idx]   = (bf16)h;
}

// ---------------------------------------------------------------------------
extern "C" void kernel_launch(void* const* d_in, const int* in_sizes, int n_in,
                              void* d_out, int out_size, void* d_ws, size_t ws_size,
                              hipStream_t stream) {
  const float* x      = (const float*)d_in[0];
  const float* hidden = (const float*)d_in[1];
  const float* enc    = (const float*)d_in[2];
  const float* W1_w   = (const float*)d_in[3];
  const float* W1_b   = (const float*)d_in[4];
  const float* W2_w   = (const float*)d_in[5];
  const float* W2_b   = (const float*)d_in[6];
  const float* V_w    = (const float*)d_in[7];
  // d_in[8] = V_b : softmax-invariant, unused
  const float* o2e_w  = (const float*)d_in[9];
  const float* o2e_b  = (const float*)d_in[10];
  const float* gru_wi = (const float*)d_in[11];
  const float* gru_wh = (const float*)d_in[12];
  const float* gru_bi = (const float*)d_in[13];
  const float* gru_bh = (const float*)d_in[14];
  const float* fc1_w  = (const float*)d_in[15];
  const float* fc1_b  = (const float*)d_in[16];
  const float* fc2_w  = (const float*)d_in[17];
  const float* fc2_b  = (const float*)d_in[18];

  float* out_main = (float*)d_out;                      // (256,4096)
  float* out_h    = out_main + (size_t)B_ * V_;         // (256,1024)
  float* out_attn = out_h + (size_t)B_ * DEC_;          // (256,128)

  // ws layout (bytes): ~21.5 MB used (enc_bf/W1_bf eliminated)
  char* ws = (char*)d_ws;
  bf16*  wi_bf   = (bf16*)(ws);                          // 9 MB
  bf16*  fc1_bf  = (bf16*)(ws + 9 * MB_);                // 1 MB
  bf16*  fc2_bf  = (bf16*)(ws + 10 * MB_);               // 4 MB
  bf16*  u_bf    = (bf16*)(ws + 14 * MB_);               // 512 KB
  bf16*  gh_bf   = (bf16*)(ws + 14 * MB_ + 524288);      // 1.5 MB
  float* e_part  = (float*)(ws + 16 * MB_);              // 512 KB
  bf16*  gi_bf   = (bf16*)(ws + 16 * MB_ + 524288);      // 1.5 MB
  bf16*  rnn_in  = (bf16*)(ws + 18 * MB_);               // 768 KB
  bf16*  tbuf    = (bf16*)(ws + 18 * MB_ + 786432);      // 256 KB
  bf16*  hnew_bf = (bf16*)(ws + 19 * MB_);               // 512 KB
  float* xe4     = (float*)(ws + 19 * MB_ + 524288);     // 2 MB

  // 1. setup: ugh + xemb GEMMs + small conversions (wi/fc1/fc2)
  setup_k<<<2176, 256, 0, stream>>>(
      hidden, W2_w, gru_wh, W1_b, W2_b, gru_bh, x, o2e_w,
      gru_wi, fc1_w, fc2_w,
      wi_bf, fc1_bf, fc2_bf, u_bf, gh_bf, xe4);

  // 2. score GEMM (f32 inputs, reg-staged 8-phase) -> e_part
  score_rs<<<512, 512, 0, stream>>>(enc, W1_w, u_bf, V_w, e_part);

  // 3. softmax + context + x_emb pack
  softmax_f<<<B_, 256, 0, stream>>>(e_part, enc, xe4, o2e_b, out_attn, rnn_in);

  // 4. gi = rnn_in @ wi^T + gru_bi (256x3072, K=1536)
  gemm_f<0, 0><<<dim3(48, 4), 256, 0, stream>>>(rnn_in, wi_bf, gru_bi, gi_bf, 1536, 3072);

  // 5. GRU gates -> h_new
  gru_f<<<(B_ * DEC_) / 256, 256, 0, stream>>>(gi_bf, gh_bf, hidden, out_h, hnew_bf);

  // 6. t = tanh(h_new @ fc1^T + fc1_b) (256x512, K=1024)
  gemm_f<1, 0><<<dim3(8, 4), 256, 0, stream>>>(hnew_bf, fc1_bf, fc1_b, tbuf, 1024, 512);

  // 7. out = t @ fc2^T + fc2_b (256x4096, K=512, f32 out)
  gemm_f<0, 1><<<dim3(64, 4), 256, 0, stream>>>(tbuf, fc2_bf, fc2_b, out_main, 512, 4096);
}